// Round 1
// baseline (175.056 us; speedup 1.0000x reference)
//
#include <hip/hip_runtime.h>
#include <hip/hip_bf16.h>

#define NPTS 8192
#define NB 4
#define NCOMBO 8

// ---------------- MFMA-path configuration ----------------
#define WPB 4                               // waves per block
#define ITILES 8                            // 16-row MFMA tiles per wave
#define ROWS_PER_WAVE (ITILES * 16)         // 128
#define ROWS_PER_BLOCK (WPB * ROWS_PER_WAVE)// 512
#define CHUNK 512                           // cols per block
#define JT (CHUNK / 16)                     // 32 col tiles
#define CHUNKS (NPTS / CHUNK)               // 16
#define ROWBLKS (NPTS / ROWS_PER_BLOCK)     // 16

using bf16x8 = __attribute__((ext_vector_type(8))) short;
using f32x4  = __attribute__((ext_vector_type(4))) float;

// bf16 round-to-nearest-even, manual (no API dependence)
__device__ __forceinline__ unsigned short bfb(float v) {
    unsigned int x = __float_as_uint(v);
    return (unsigned short)((x + 0x7FFFu + ((x >> 16) & 1u)) >> 16);
}
__device__ __forceinline__ float bff(unsigned short u) {
    return __uint_as_float(((unsigned int)u) << 16);
}

// ---------------------------------------------------------------------------
// Encode each point into a K=32 bf16 vector such that
// dot(Arow(p), Bcol(t)) == |p|^2 - 2 p.t + |t|^2  to ~1e-6.
// 3-way split h+m+l of each value captures the full fp32 mantissa; bf16
// products are exact in fp32, so only the tiny dropped cross terms remain.
// Per coordinate (a = -2p on the A side, t on the B side), 6 K-slots:
//   A: [ah ah am ah al am]   B: [th tm th tl th tm]
// slots 18..20: A=[pph ppm ppl] B=[1 1 1];  21..23: A=[1 1 1] B=[tth ttm ttl]
// ---------------------------------------------------------------------------
__global__ __launch_bounds__(256) void encode_pts(
    const float* __restrict__ pred, const float* __restrict__ target,
    unsigned short* __restrict__ Aenc, unsigned short* __restrict__ Benc)
{
    const int idx  = blockIdx.x * 256 + threadIdx.x;   // 0..65535
    const int side = idx >> 15;                        // 0 = pred/A, 1 = target/B
    const int p    = idx & 32767;                      // flat [b][pt]
    const float* src = side ? target : pred;
    float x = src[3 * (size_t)p + 0];
    float y = src[3 * (size_t)p + 1];
    float z = src[3 * (size_t)p + 2];
    float pp = fmaf(x, x, fmaf(y, y, z * z));

    union { unsigned short e[32]; uint4 q[4]; } u;
#pragma unroll
    for (int i = 0; i < 32; i++) u.e[i] = 0;

    float cs[3];
    cs[0] = side ? x : -2.f * x;
    cs[1] = side ? y : -2.f * y;
    cs[2] = side ? z : -2.f * z;
#pragma unroll
    for (int c = 0; c < 3; c++) {
        float v = cs[c];
        unsigned short H = bfb(v); float hf = bff(H);
        float r = v - hf;                       // exact
        unsigned short M = bfb(r); float mf = bff(M);
        unsigned short L = bfb(r - mf);         // exact residual
        if (side == 0) {
            u.e[6*c+0] = H; u.e[6*c+1] = H; u.e[6*c+2] = M;
            u.e[6*c+3] = H; u.e[6*c+4] = L; u.e[6*c+5] = M;
        } else {
            u.e[6*c+0] = H; u.e[6*c+1] = M; u.e[6*c+2] = H;
            u.e[6*c+3] = L; u.e[6*c+4] = H; u.e[6*c+5] = M;
        }
    }
    {
        unsigned short H = bfb(pp); float hf = bff(H);
        float r = pp - hf;
        unsigned short M = bfb(r); float mf = bff(M);
        unsigned short L = bfb(r - mf);
        const unsigned short ONE = 0x3F80u;
        if (side == 0) {
            u.e[18] = H;   u.e[19] = M;   u.e[20] = L;
            u.e[21] = ONE; u.e[22] = ONE; u.e[23] = ONE;
        } else {
            u.e[18] = ONE; u.e[19] = ONE; u.e[20] = ONE;
            u.e[21] = H;   u.e[22] = M;   u.e[23] = L;
        }
    }
    uint4* dst = (uint4*)((side ? Benc : Aenc) + (size_t)p * 32);
    dst[0] = u.q[0]; dst[1] = u.q[1]; dst[2] = u.q[2]; dst[3] = u.q[3];
}

// ---------------------------------------------------------------------------
// Main kernel: one wave = 128 rows (8 A-frags in regs), streams 16-col B-tiles
// across a 512-col chunk. Each mfma_f32_16x16x32_bf16 yields a full 16x16 d2
// tile (C/D layout: col = lane&15, row = (lane>>4)*4 + reg). Row-mins stay in
// registers across the chunk; col-mins reduce via shfl_xor + LDS atomicMin.
// ---------------------------------------------------------------------------
__device__ __forceinline__ void tile_step(
    const bf16x8 (&af)[ITILES], bf16x8 bf, f32x4 (&rmin)[ITILES],
    unsigned int* ldscol, int colw, int lane, const f32x4& zf)
{
    f32x4 cp = {3e38f, 3e38f, 3e38f, 3e38f};
#pragma unroll
    for (int it = 0; it < ITILES; ++it) {
        f32x4 d = __builtin_amdgcn_mfma_f32_16x16x32_bf16(af[it], bf, zf, 0, 0, 0);
#pragma unroll
        for (int r = 0; r < 4; ++r) {
            rmin[it][r] = fminf(rmin[it][r], d[r]);   // row-min (over cols)
            cp[r]       = fminf(cp[r], d[r]);         // col-min partial (over rows)
        }
    }
    float cm = fminf(fminf(cp[0], cp[1]), fminf(cp[2], cp[3]));
    cm = fminf(cm, __shfl_xor(cm, 16, 64));
    cm = fminf(cm, __shfl_xor(cm, 32, 64));
    if (lane < 16)
        atomicMin(&ldscol[colw + lane], __float_as_uint(cm));
}

__global__ __launch_bounds__(256, 4) void chamfer_mfma(
    const unsigned short* __restrict__ Aenc,
    const unsigned short* __restrict__ Benc,
    unsigned int* __restrict__ partmin)
{
    __shared__ unsigned int ldscol[CHUNK];
    const int tid  = threadIdx.x;
    const int lane = tid & 63;
    const int w    = tid >> 6;
    const int bid  = blockIdx.x;
    const int ck   = bid & (CHUNKS - 1);
    const int rb   = (bid >> 4) & (ROWBLKS - 1);
    const int b    = bid >> 8;

    for (int i = tid; i < CHUNK; i += 256) ldscol[i] = 0x7F7F7F7Fu;

    const int row0 = rb * ROWS_PER_BLOCK + w * ROWS_PER_WAVE;
    const int col0 = ck * CHUNK;

    // A fragments: lane&15 = row-in-tile, (lane>>4)*8 = K block
    const unsigned short* ap =
        Aenc + ((size_t)(b * NPTS + row0 + (lane & 15))) * 32 + ((lane >> 4) * 8);
    bf16x8 af[ITILES];
#pragma unroll
    for (int it = 0; it < ITILES; ++it)
        af[it] = *(const bf16x8*)(ap + (size_t)it * 16 * 32);

    f32x4 rmin[ITILES];
#pragma unroll
    for (int it = 0; it < ITILES; ++it) {
        rmin[it][0] = 3e38f; rmin[it][1] = 3e38f;
        rmin[it][2] = 3e38f; rmin[it][3] = 3e38f;
    }
    const f32x4 zf = {0.f, 0.f, 0.f, 0.f};

    const unsigned short* bp =
        Benc + ((size_t)(b * NPTS + col0 + (lane & 15))) * 32 + ((lane >> 4) * 8);

    __syncthreads();  // ldscol init visible to all waves

    // 2-deep prefetch, unroll-2 (named regs, no dynamic indexing)
    bf16x8 B0 = *(const bf16x8*)(bp);
    bf16x8 B1 = *(const bf16x8*)(bp + 512);
    bp += 1024;
    int colw = 0;
    for (int jt = 0; jt < JT; jt += 2) {
        bf16x8 Bn0 = *(const bf16x8*)(bp);        // last iter reads 2KB past
        bf16x8 Bn1 = *(const bf16x8*)(bp + 512);  // chunk: ws padded, unused
        bp += 1024;
        tile_step(af, B0, rmin, ldscol, colw, lane, zf); colw += 16;
        tile_step(af, B1, rmin, ldscol, colw, lane, zf); colw += 16;
        B0 = Bn0; B1 = Bn1;
    }

    // row-min epilogue: reduce across the 16 col lanes, then global atomicMin
#pragma unroll
    for (int it = 0; it < ITILES; ++it) {
#pragma unroll
        for (int r = 0; r < 4; ++r) {
            float v = rmin[it][r];
            v = fminf(v, __shfl_xor(v, 1, 64));
            v = fminf(v, __shfl_xor(v, 2, 64));
            v = fminf(v, __shfl_xor(v, 4, 64));
            v = fminf(v, __shfl_xor(v, 8, 64));
            if ((lane & 15) == 0) {
                int row = row0 + it * 16 + (lane >> 4) * 4 + r;
                atomicMin(&partmin[(size_t)(2 * b) * NPTS + row], __float_as_uint(v));
            }
        }
    }

    // col-min epilogue: merge block-local LDS mins into global
    __syncthreads();
    for (int i = tid; i < CHUNK; i += 256)
        atomicMin(&partmin[(size_t)(2 * b + 1) * NPTS + col0 + i], ldscol[i]);
}

// ---------------------------------------------------------------------------
// Fallback: previous best VALU kernel (used only if workspace is too small)
// ---------------------------------------------------------------------------
#define T 256
#define Q 8
#define S 16
#define CH 512

__global__ __launch_bounds__(T) void chamfer_partial(
    const float* __restrict__ pred, const float* __restrict__ target,
    unsigned int* __restrict__ partmin)
{
    __shared__ float4 db[CH + 2];

    const int bid   = blockIdx.x;
    const int dbc   = bid & (S - 1);
    const int qc    = (bid >> 4) & 3;
    const int combo = bid >> 6;
    const int dir   = combo & 1;
    const int b     = combo >> 1;

    const float* qptr = (dir == 0 ? pred : target) + (size_t)b * NPTS * 3;
    const float* dptr = (dir == 0 ? target : pred) + (size_t)b * NPTS * 3;

    const int tid = threadIdx.x;

    for (int p = tid; p < CH; p += T) {
        int gj = dbc * CH + p;
        float x = dptr[gj * 3 + 0];
        float y = dptr[gj * 3 + 1];
        float z = dptr[gj * 3 + 2];
        db[p] = make_float4(-2.f * x, -2.f * y, -2.f * z,
                            x * x + y * y + z * z);
    }

    float qx[Q], qy[Q], qz[Q], m[Q];
    int qi0 = qc * (T * Q) + tid;
#pragma unroll
    for (int k = 0; k < Q; k++) {
        int qi = qi0 + k * T;
        qx[k] = qptr[qi * 3 + 0];
        qy[k] = qptr[qi * 3 + 1];
        qz[k] = qptr[qi * 3 + 2];
        m[k]  = 3.4e38f;
    }
    __syncthreads();

    float4 c0 = db[0], c1 = db[1];
    for (int j = 0; j < CH; j += 2) {
        float4 n0 = db[j + 2];
        float4 n1 = db[j + 3];
#pragma unroll
        for (int k = 0; k < Q; k++) {
            float s0 = fmaf(c0.x, qx[k], fmaf(c0.y, qy[k], fmaf(c0.z, qz[k], c0.w)));
            float s1 = fmaf(c1.x, qx[k], fmaf(c1.y, qy[k], fmaf(c1.z, qz[k], c1.w)));
            m[k] = fminf(m[k], fminf(s0, s1));
        }
        c0 = n0; c1 = n1;
    }

#pragma unroll
    for (int k = 0; k < Q; k++) {
        int qi = qi0 + k * T;
        float qq = fmaf(qx[k], qx[k], fmaf(qy[k], qy[k], qz[k] * qz[k]));
        float d2 = fmaxf(m[k] + qq, 0.0f);
        atomicMin(&partmin[combo * NPTS + qi], __float_as_uint(d2));
    }
}

__global__ __launch_bounds__(1024) void reduce_final(
    const unsigned int* __restrict__ partmin,
    const float* __restrict__ bpp, const float* __restrict__ lamda,
    float* __restrict__ out)
{
    const int tid = threadIdx.x;
    float s = 0.f;
#pragma unroll
    for (int k = 0; k < (NCOMBO * NPTS) / 1024; k++)
        s += __uint_as_float(partmin[tid + k * 1024]);

#pragma unroll
    for (int off = 32; off > 0; off >>= 1)
        s += __shfl_down(s, off, 64);

    __shared__ float red[16];
    int lane = tid & 63, wid = tid >> 6;
    if (lane == 0) red[wid] = s;
    __syncthreads();
    if (wid == 0) {
        s = (lane < 16) ? red[lane] : 0.f;
#pragma unroll
        for (int off = 8; off > 0; off >>= 1)
            s += __shfl_down(s, off, 64);
        if (lane == 0)
            out[0] = s * (1.0f / 32768.0f) + lamda[0] * bpp[0];
    }
}

extern "C" void kernel_launch(void* const* d_in, const int* in_sizes, int n_in,
                              void* d_out, int out_size, void* d_ws, size_t ws_size,
                              hipStream_t stream) {
    const float* pred   = (const float*)d_in[0];
    const float* target = (const float*)d_in[1];
    const float* bpp    = (const float*)d_in[2];
    const float* lamda  = (const float*)d_in[3];

    unsigned int* partmin = (unsigned int*)d_ws;
    const size_t partmin_bytes = (size_t)NCOMBO * NPTS * sizeof(unsigned int); // 256 KB
    const size_t enc_bytes     = (size_t)NB * NPTS * 32 * sizeof(unsigned short); // 2 MB each
    const size_t needed = partmin_bytes + 2 * enc_bytes + 4096; // + prefetch slack

    hipMemsetAsync(partmin, 0x7F, partmin_bytes, stream);

    if (ws_size >= needed) {
        unsigned short* Aenc = (unsigned short*)((char*)d_ws + partmin_bytes);
        unsigned short* Benc = Aenc + (size_t)NB * NPTS * 32;
        encode_pts<<<(2 * NB * NPTS) / 256, 256, 0, stream>>>(pred, target, Aenc, Benc);
        chamfer_mfma<<<NB * ROWBLKS * CHUNKS, 256, 0, stream>>>(Aenc, Benc, partmin);
    } else {
        chamfer_partial<<<NCOMBO * 4 * S, T, 0, stream>>>(pred, target, partmin);
    }
    reduce_final<<<1, 1024, 0, stream>>>(partmin, bpp, lamda, (float*)d_out);
}

// Round 2
// 94.449 us; speedup vs baseline: 1.8535x; 1.8535x over previous
//
#include <hip/hip_runtime.h>
#include <hip/hip_bf16.h>

#define NPTS 8192
#define NB 4
#define NCOMBO 8

// ---------------- MFMA-path configuration ----------------
#define WPB 4                               // waves per block
#define ITILES 8                            // 16-row MFMA tiles per wave
#define ROWS_PER_WAVE (ITILES * 16)         // 128
#define ROWS_PER_BLOCK (WPB * ROWS_PER_WAVE)// 512
#define CHUNK 512                           // cols per block
#define JT (CHUNK / 16)                     // 32 col tiles
#define CHUNKS (NPTS / CHUNK)               // 16
#define ROWBLKS (NPTS / ROWS_PER_BLOCK)     // 16

using bf16x8 = __attribute__((ext_vector_type(8))) short;
using f32x4  = __attribute__((ext_vector_type(4))) float;

// bf16 round-to-nearest-even, manual
__device__ __forceinline__ unsigned short bfb(float v) {
    unsigned int x = __float_as_uint(v);
    return (unsigned short)((x + 0x7FFFu + ((x >> 16) & 1u)) >> 16);
}
__device__ __forceinline__ float bff(unsigned short u) {
    return __uint_as_float(((unsigned int)u) << 16);
}

// ---------------------------------------------------------------------------
// Encode each point into a K=32 bf16 vector such that
// dot(Arow(p), Bcol(t)) == |p|^2 - 2 p.t + |t|^2  to ~1e-6.
// (verified on HW: round-1 absmax 0.0)
// ---------------------------------------------------------------------------
__global__ __launch_bounds__(256) void encode_pts(
    const float* __restrict__ pred, const float* __restrict__ target,
    unsigned short* __restrict__ Aenc, unsigned short* __restrict__ Benc)
{
    const int idx  = blockIdx.x * 256 + threadIdx.x;   // 0..65535
    const int side = idx >> 15;                        // 0 = pred/A, 1 = target/B
    const int p    = idx & 32767;                      // flat [b][pt]
    const float* src = side ? target : pred;
    float x = src[3 * (size_t)p + 0];
    float y = src[3 * (size_t)p + 1];
    float z = src[3 * (size_t)p + 2];
    float pp = fmaf(x, x, fmaf(y, y, z * z));

    union { unsigned short e[32]; uint4 q[4]; } u;
#pragma unroll
    for (int i = 0; i < 32; i++) u.e[i] = 0;

    float cs[3];
    cs[0] = side ? x : -2.f * x;
    cs[1] = side ? y : -2.f * y;
    cs[2] = side ? z : -2.f * z;
#pragma unroll
    for (int c = 0; c < 3; c++) {
        float v = cs[c];
        unsigned short H = bfb(v); float hf = bff(H);
        float r = v - hf;
        unsigned short M = bfb(r); float mf = bff(M);
        unsigned short L = bfb(r - mf);
        if (side == 0) {
            u.e[6*c+0] = H; u.e[6*c+1] = H; u.e[6*c+2] = M;
            u.e[6*c+3] = H; u.e[6*c+4] = L; u.e[6*c+5] = M;
        } else {
            u.e[6*c+0] = H; u.e[6*c+1] = M; u.e[6*c+2] = H;
            u.e[6*c+3] = L; u.e[6*c+4] = H; u.e[6*c+5] = M;
        }
    }
    {
        unsigned short H = bfb(pp); float hf = bff(H);
        float r = pp - hf;
        unsigned short M = bfb(r); float mf = bff(M);
        unsigned short L = bfb(r - mf);
        const unsigned short ONE = 0x3F80u;
        if (side == 0) {
            u.e[18] = H;   u.e[19] = M;   u.e[20] = L;
            u.e[21] = ONE; u.e[22] = ONE; u.e[23] = ONE;
        } else {
            u.e[18] = ONE; u.e[19] = ONE; u.e[20] = ONE;
            u.e[21] = H;   u.e[22] = M;   u.e[23] = L;
        }
    }
    uint4* dst = (uint4*)((side ? Benc : Aenc) + (size_t)p * 32);
    dst[0] = u.q[0]; dst[1] = u.q[1]; dst[2] = u.q[2]; dst[3] = u.q[3];
}

// ---------------------------------------------------------------------------
// 2x2 tile group: 4 MFMAs share min3-style reduction -> ~1 VALU op per elem.
// Col partials go straight to LDS ds_min from all 64 lanes (no shfl chain).
// ---------------------------------------------------------------------------
__device__ __forceinline__ void tile_pair(
    const bf16x8 (&af)[ITILES], bf16x8 b0, bf16x8 b1,
    f32x4 (&rmin)[ITILES], unsigned int* ldscol, int colw, int lane,
    const f32x4& zf)
{
    f32x4 cp0 = {3e38f, 3e38f, 3e38f, 3e38f};
    f32x4 cp1 = {3e38f, 3e38f, 3e38f, 3e38f};
#pragma unroll
    for (int it = 0; it < ITILES; it += 2) {
        f32x4 d00 = __builtin_amdgcn_mfma_f32_16x16x32_bf16(af[it],     b0, zf, 0, 0, 0);
        f32x4 d01 = __builtin_amdgcn_mfma_f32_16x16x32_bf16(af[it],     b1, zf, 0, 0, 0);
        f32x4 d10 = __builtin_amdgcn_mfma_f32_16x16x32_bf16(af[it + 1], b0, zf, 0, 0, 0);
        f32x4 d11 = __builtin_amdgcn_mfma_f32_16x16x32_bf16(af[it + 1], b1, zf, 0, 0, 0);
#pragma unroll
        for (int r = 0; r < 4; ++r) {
            rmin[it][r]     = fminf(fminf(d00[r], d01[r]), rmin[it][r]);     // min3
            rmin[it + 1][r] = fminf(fminf(d10[r], d11[r]), rmin[it + 1][r]); // min3
            cp0[r]          = fminf(fminf(d00[r], d10[r]), cp0[r]);          // min3
            cp1[r]          = fminf(fminf(d01[r], d11[r]), cp1[r]);          // min3
        }
    }
    float c0 = fminf(fminf(cp0[0], cp0[1]), fminf(cp0[2], cp0[3]));
    float c1 = fminf(fminf(cp1[0], cp1[1]), fminf(cp1[2], cp1[3]));
    c0 = fmaxf(c0, 0.f);           // keep bit-pattern uint-min == float-min
    c1 = fmaxf(c1, 0.f);
    atomicMin(&ldscol[colw + (lane & 15)],      __float_as_uint(c0)); // 4-way/addr, LDS
    atomicMin(&ldscol[colw + 16 + (lane & 15)], __float_as_uint(c1));
}

// MODE 0: plain-store partials (no global atomics).  MODE 1: atomic partmin.
template <int MODE>
__global__ __launch_bounds__(256, 4) void chamfer_mfma(
    const unsigned short* __restrict__ Aenc,
    const unsigned short* __restrict__ Benc,
    unsigned int* __restrict__ partmin,
    float* __restrict__ rowpart,
    float* __restrict__ colpart)
{
    __shared__ unsigned int ldscol[CHUNK];       // 2 KB
    __shared__ float        ldsrow[ROWS_PER_BLOCK]; // 2 KB
    const int tid  = threadIdx.x;
    const int lane = tid & 63;
    const int w    = tid >> 6;
    const int bid  = blockIdx.x;
    const int ck   = bid & (CHUNKS - 1);
    const int rb   = (bid >> 4) & (ROWBLKS - 1);
    const int b    = bid >> 8;

    for (int i = tid; i < CHUNK; i += 256) ldscol[i] = 0x7F7F7F7Fu;

    const int row0 = rb * ROWS_PER_BLOCK + w * ROWS_PER_WAVE;
    const int col0 = ck * CHUNK;

    // A fragments: lane&15 = row-in-tile, (lane>>4)*8 = K block (HW-verified)
    const unsigned short* ap =
        Aenc + ((size_t)(b * NPTS + row0 + (lane & 15))) * 32 + ((lane >> 4) * 8);
    bf16x8 af[ITILES];
#pragma unroll
    for (int it = 0; it < ITILES; ++it)
        af[it] = *(const bf16x8*)(ap + (size_t)it * 16 * 32);

    f32x4 rmin[ITILES];
#pragma unroll
    for (int it = 0; it < ITILES; ++it) {
        rmin[it][0] = 3e38f; rmin[it][1] = 3e38f;
        rmin[it][2] = 3e38f; rmin[it][3] = 3e38f;
    }
    const f32x4 zf = {0.f, 0.f, 0.f, 0.f};

    const unsigned short* bp =
        Benc + ((size_t)(b * NPTS + col0 + (lane & 15))) * 32 + ((lane >> 4) * 8);

    __syncthreads();  // ldscol init visible

    // 2-tile-pair prefetch pipeline
    bf16x8 B0 = *(const bf16x8*)(bp);
    bf16x8 B1 = *(const bf16x8*)(bp + 512);
    bp += 1024;
    int colw = 0;
    for (int jt = 0; jt < JT; jt += 2) {
        bf16x8 Bn0 = *(const bf16x8*)(bp);        // last iter reads 2 tiles past
        bf16x8 Bn1 = *(const bf16x8*)(bp + 512);  // chunk end: ws region, unused
        bp += 1024;
        tile_pair(af, B0, B1, rmin, ldscol, colw, lane, zf);
        colw += 32;
        B0 = Bn0; B1 = Bn1;
    }

    // row-min epilogue: reduce the 16 col lanes, stage in LDS, coalesced store
#pragma unroll
    for (int it = 0; it < ITILES; ++it) {
#pragma unroll
        for (int r = 0; r < 4; ++r) {
            float v = rmin[it][r];
            v = fminf(v, __shfl_xor(v, 1, 64));
            v = fminf(v, __shfl_xor(v, 2, 64));
            v = fminf(v, __shfl_xor(v, 4, 64));
            v = fminf(v, __shfl_xor(v, 8, 64));
            if ((lane & 15) == 0) {
                int rloc = it * 16 + (lane >> 4) * 4 + r;   // row within wave
                if constexpr (MODE == 0) {
                    ldsrow[w * ROWS_PER_WAVE + rloc] = fmaxf(v, 0.f);
                } else {
                    atomicMin(&partmin[(size_t)(2 * b) * NPTS + row0 + rloc],
                              __float_as_uint(fmaxf(v, 0.f)));
                }
            }
        }
    }

    __syncthreads();
    if constexpr (MODE == 0) {
        // rowpart[b][ck][row], colpart[b][rb][col] — disjoint, plain stores
        for (int i = tid; i < ROWS_PER_BLOCK; i += 256)
            rowpart[((size_t)(b * CHUNKS) + ck) * NPTS + rb * ROWS_PER_BLOCK + i]
                = ldsrow[i];
        for (int i = tid; i < CHUNK; i += 256)
            colpart[((size_t)(b * ROWBLKS) + rb) * NPTS + col0 + i]
                = __uint_as_float(ldscol[i]);
    } else {
        for (int i = tid; i < CHUNK; i += 256)
            atomicMin(&partmin[(size_t)(2 * b + 1) * NPTS + col0 + i], ldscol[i]);
    }
}

// min over 16 slices for every row/col cell, then partial sums (64 blocks)
__global__ __launch_bounds__(256) void reduce_partials(
    const float* __restrict__ rowpart, const float* __restrict__ colpart,
    float* __restrict__ bsum)
{
    const int tid = threadIdx.x;
    const int gt  = blockIdx.x * 256 + tid;    // 0..16383
    float s = 0.f;
#pragma unroll
    for (int a = 0; a < 2; a++) {
        const float* P = a ? colpart : rowpart;
#pragma unroll
        for (int cc = 0; cc < 2; cc++) {
            int c = gt + cc * 16384;           // 0..32767
            int b = c >> 13, r = c & 8191;
            const float* p = P + (size_t)b * 16 * NPTS + r;
            float m = p[0];
#pragma unroll
            for (int k = 1; k < 16; k++)
                m = fminf(m, p[(size_t)k * NPTS]);
            s += m;
        }
    }
#pragma unroll
    for (int off = 32; off > 0; off >>= 1) s += __shfl_down(s, off, 64);
    __shared__ float red[4];
    int lane = tid & 63, wid = tid >> 6;
    if (lane == 0) red[wid] = s;
    __syncthreads();
    if (tid == 0) bsum[blockIdx.x] = red[0] + red[1] + red[2] + red[3];
}

__global__ void final_sum(const float* __restrict__ bsum,
    const float* __restrict__ bpp, const float* __restrict__ lamda,
    float* __restrict__ out)
{
    int lane = threadIdx.x;                    // 64 threads
    float s = bsum[lane];
#pragma unroll
    for (int off = 32; off > 0; off >>= 1) s += __shfl_down(s, off, 64);
    if (lane == 0) out[0] = s * (1.0f / 32768.0f) + lamda[0] * bpp[0];
}

// ---------------------------------------------------------------------------
// Fallback: previous VALU kernel (tiny workspace only)
// ---------------------------------------------------------------------------
#define T 256
#define Q 8
#define S 16
#define CH 512

__global__ __launch_bounds__(T) void chamfer_partial(
    const float* __restrict__ pred, const float* __restrict__ target,
    unsigned int* __restrict__ partmin)
{
    __shared__ float4 db[CH + 2];

    const int bid   = blockIdx.x;
    const int dbc   = bid & (S - 1);
    const int qc    = (bid >> 4) & 3;
    const int combo = bid >> 6;
    const int dir   = combo & 1;
    const int b     = combo >> 1;

    const float* qptr = (dir == 0 ? pred : target) + (size_t)b * NPTS * 3;
    const float* dptr = (dir == 0 ? target : pred) + (size_t)b * NPTS * 3;

    const int tid = threadIdx.x;

    for (int p = tid; p < CH; p += T) {
        int gj = dbc * CH + p;
        float x = dptr[gj * 3 + 0];
        float y = dptr[gj * 3 + 1];
        float z = dptr[gj * 3 + 2];
        db[p] = make_float4(-2.f * x, -2.f * y, -2.f * z,
                            x * x + y * y + z * z);
    }

    float qx[Q], qy[Q], qz[Q], m[Q];
    int qi0 = qc * (T * Q) + tid;
#pragma unroll
    for (int k = 0; k < Q; k++) {
        int qi = qi0 + k * T;
        qx[k] = qptr[qi * 3 + 0];
        qy[k] = qptr[qi * 3 + 1];
        qz[k] = qptr[qi * 3 + 2];
        m[k]  = 3.4e38f;
    }
    __syncthreads();

    float4 c0 = db[0], c1 = db[1];
    for (int j = 0; j < CH; j += 2) {
        float4 n0 = db[j + 2];
        float4 n1 = db[j + 3];
#pragma unroll
        for (int k = 0; k < Q; k++) {
            float s0 = fmaf(c0.x, qx[k], fmaf(c0.y, qy[k], fmaf(c0.z, qz[k], c0.w)));
            float s1 = fmaf(c1.x, qx[k], fmaf(c1.y, qy[k], fmaf(c1.z, qz[k], c1.w)));
            m[k] = fminf(m[k], fminf(s0, s1));
        }
        c0 = n0; c1 = n1;
    }

#pragma unroll
    for (int k = 0; k < Q; k++) {
        int qi = qi0 + k * T;
        float qq = fmaf(qx[k], qx[k], fmaf(qy[k], qy[k], qz[k] * qz[k]));
        float d2 = fmaxf(m[k] + qq, 0.0f);
        atomicMin(&partmin[combo * NPTS + qi], __float_as_uint(d2));
    }
}

__global__ __launch_bounds__(1024) void reduce_final(
    const unsigned int* __restrict__ partmin,
    const float* __restrict__ bpp, const float* __restrict__ lamda,
    float* __restrict__ out)
{
    const int tid = threadIdx.x;
    float s = 0.f;
#pragma unroll
    for (int k = 0; k < (NCOMBO * NPTS) / 1024; k++)
        s += __uint_as_float(partmin[tid + k * 1024]);

#pragma unroll
    for (int off = 32; off > 0; off >>= 1)
        s += __shfl_down(s, off, 64);

    __shared__ float red[16];
    int lane = tid & 63, wid = tid >> 6;
    if (lane == 0) red[wid] = s;
    __syncthreads();
    if (wid == 0) {
        s = (lane < 16) ? red[lane] : 0.f;
#pragma unroll
        for (int off = 8; off > 0; off >>= 1)
            s += __shfl_down(s, off, 64);
        if (lane == 0)
            out[0] = s * (1.0f / 32768.0f) + lamda[0] * bpp[0];
    }
}

extern "C" void kernel_launch(void* const* d_in, const int* in_sizes, int n_in,
                              void* d_out, int out_size, void* d_ws, size_t ws_size,
                              hipStream_t stream) {
    const float* pred   = (const float*)d_in[0];
    const float* target = (const float*)d_in[1];
    const float* bpp    = (const float*)d_in[2];
    const float* lamda  = (const float*)d_in[3];

    const size_t enc_bytes  = (size_t)NB * NPTS * 32 * sizeof(unsigned short); // 2 MB
    const size_t part_bytes = (size_t)NB * 16 * NPTS * sizeof(float);          // 2 MB
    const size_t pm_bytes   = (size_t)NCOMBO * NPTS * sizeof(unsigned int);    // 256 KB

    const size_t need0 = 2 * enc_bytes + 2 * part_bytes + 4096 + 4096;  // ~8 MB
    const size_t need1 = pm_bytes + 2 * enc_bytes + 4096;               // ~4.3 MB

    if (ws_size >= need0) {
        unsigned short* Aenc = (unsigned short*)d_ws;
        unsigned short* Benc = Aenc + (size_t)NB * NPTS * 32;
        float* rowpart = (float*)((char*)d_ws + 2 * enc_bytes);
        float* colpart = rowpart + (size_t)NB * 16 * NPTS;
        float* bsum    = colpart + (size_t)NB * 16 * NPTS;
        encode_pts<<<(2 * NB * NPTS) / 256, 256, 0, stream>>>(pred, target, Aenc, Benc);
        chamfer_mfma<0><<<NB * ROWBLKS * CHUNKS, 256, 0, stream>>>(
            Aenc, Benc, nullptr, rowpart, colpart);
        reduce_partials<<<64, 256, 0, stream>>>(rowpart, colpart, bsum);
        final_sum<<<1, 64, 0, stream>>>(bsum, bpp, lamda, (float*)d_out);
    } else if (ws_size >= need1) {
        unsigned int* partmin = (unsigned int*)d_ws;
        unsigned short* Aenc = (unsigned short*)((char*)d_ws + pm_bytes);
        unsigned short* Benc = Aenc + (size_t)NB * NPTS * 32;
        hipMemsetAsync(partmin, 0x7F, pm_bytes, stream);
        encode_pts<<<(2 * NB * NPTS) / 256, 256, 0, stream>>>(pred, target, Aenc, Benc);
        chamfer_mfma<1><<<NB * ROWBLKS * CHUNKS, 256, 0, stream>>>(
            Aenc, Benc, partmin, nullptr, nullptr);
        reduce_final<<<1, 1024, 0, stream>>>(partmin, bpp, lamda, (float*)d_out);
    } else {
        unsigned int* partmin = (unsigned int*)d_ws;
        hipMemsetAsync(partmin, 0x7F, pm_bytes, stream);
        chamfer_partial<<<NCOMBO * 4 * S, T, 0, stream>>>(pred, target, partmin);
        reduce_final<<<1, 1024, 0, stream>>>(partmin, bpp, lamda, (float*)d_out);
    }
}